// Round 2
// baseline (233.903 us; speedup 1.0000x reference)
//
#include <hip/hip_runtime.h>

// Both slice_sites and addr2site_map are sorted (jnp.sort in setup_inputs).
// Membership of sorted A in sorted B = partitioned merge-join:
//   found(s) <=> exists j with a2s[j]==s && sig[j]>0
// which matches the reference's sentinel+searchsorted exactly (site ids >= 0
// never collide with the -1 sentinel; searchsorted 'left' + clip + equality
// check is plain membership in the sig>0-filtered set).

static constexpr int EPT   = 16;            // elements per thread (4 x int4)
static constexpr int BLOCK = 256;
static constexpr int TILE  = BLOCK * EPT;   // 4096 elements per block
static constexpr int LROW  = EPT + 1;       // padded LDS row (stride 17 -> conflict-free)

__global__ __launch_bounds__(BLOCK) void merge_join_kernel(
    const int*   __restrict__ slice_sites,
    const int*   __restrict__ sig,
    const int*   __restrict__ a2s,
    const float* __restrict__ scores,
    float*       __restrict__ rem,
    float*       __restrict__ avail,
    int n_slice, int n_clb)
{
    __shared__ float s_rem[BLOCK * LROW];   // 17,408 B
    __shared__ float s_av [BLOCK * LROW];   // 17,408 B

    const int blockBase = blockIdx.x * TILE;
    const int base      = blockBase + threadIdx.x * EPT;
    const bool active   = (base + EPT) <= n_slice;

    if (active) {
        // Vectorized load of this thread's 16 slice ids + 16 scores.
        int   sv[EPT];
        float fv[EPT];
        const int4*   sp = (const int4*)(slice_sites + base);
        const float4* cp = (const float4*)(scores + base);
#pragma unroll
        for (int q = 0; q < EPT / 4; ++q) {
            int4 a = sp[q];
            sv[4*q+0] = a.x; sv[4*q+1] = a.y; sv[4*q+2] = a.z; sv[4*q+3] = a.w;
            float4 b = cp[q];
            fv[4*q+0] = b.x; fv[4*q+1] = b.y; fv[4*q+2] = b.z; fv[4*q+3] = b.w;
        }

        // Binary search: first j with a2s[j] >= sv[0].
        int lo = 0, hi = n_clb;
        const int key = sv[0];
        while (lo < hi) {
            int mid = (lo + hi) >> 1;
            if (a2s[mid] < key) lo = mid + 1; else hi = mid;
        }
        int j = lo;

        const int lbase = threadIdx.x * LROW;
#pragma unroll 1
        for (int k = 0; k < EPT; ++k) {
            const int s = sv[k];
            while (j < n_clb && a2s[j] < s) ++j;
            // Scan the equal-value run for any sig>0 entry. Do NOT advance j
            // past the run start: slice_sites may contain duplicates.
            bool found = false;
            int jj = j;
            while (jj < n_clb && a2s[jj] == s) {
                if (sig[jj] > 0) { found = true; break; }
                ++jj;
            }
            s_rem[lbase + k] = found ? 0.0f : 1.0f;
            s_av [lbase + k] = found ? 0.0f : fv[k];
        }
    }
    __syncthreads();

    // Coalesced writeback. Global element g of this tile lives at LDS index
    // g + (g>>4) (the per-row +1 pad). Consecutive lanes -> ~consecutive LDS
    // addresses (stride 1 with occasional +2) -> at worst free 2-way conflicts.
    const int valid = min(TILE, n_slice - blockBase);
    float* orem = rem   + blockBase;
    float* oav  = avail + blockBase;
    for (int g = threadIdx.x; g < valid; g += BLOCK) {
        const int l = g + (g >> 4);
        orem[g] = s_rem[l];
        oav [g] = s_av [l];
    }
}

// Scalar fallback for any ragged tail (n_slice not divisible by EPT).
__global__ void tail_kernel(
    const int*   __restrict__ slice_sites,
    const int*   __restrict__ sig,
    const int*   __restrict__ a2s,
    const float* __restrict__ scores,
    float*       __restrict__ rem,
    float*       __restrict__ avail,
    int start, int n_slice, int n_clb)
{
    int i = start + blockIdx.x * blockDim.x + threadIdx.x;
    if (i >= n_slice) return;
    const int s = slice_sites[i];
    int lo = 0, hi = n_clb;
    while (lo < hi) {
        int mid = (lo + hi) >> 1;
        if (a2s[mid] < s) lo = mid + 1; else hi = mid;
    }
    bool found = false;
    while (lo < n_clb && a2s[lo] == s) {
        if (sig[lo] > 0) { found = true; break; }
        ++lo;
    }
    rem[i]   = found ? 0.0f : 1.0f;
    avail[i] = found ? 0.0f : scores[i];
}

extern "C" void kernel_launch(void* const* d_in, const int* in_sizes, int n_in,
                              void* d_out, int out_size, void* d_ws, size_t ws_size,
                              hipStream_t stream) {
    const int*   slice_sites = (const int*)d_in[0];
    const int*   sig         = (const int*)d_in[1];
    const int*   a2s         = (const int*)d_in[2];
    const float* scores      = (const float*)d_in[3];
    const int n_slice = in_sizes[0];
    const int n_clb   = in_sizes[1];

    float* rem   = (float*)d_out;
    float* avail = rem + n_slice;

    const int n_main = (n_slice / EPT) * EPT;   // 6M is divisible by 16
    if (n_main > 0) {
        const int blocks = (n_main + TILE - 1) / TILE;
        merge_join_kernel<<<blocks, BLOCK, 0, stream>>>(
            slice_sites, sig, a2s, scores, rem, avail, n_main, n_clb);
    }
    if (n_main < n_slice) {
        const int tail = n_slice - n_main;
        tail_kernel<<<(tail + 63) / 64, 64, 0, stream>>>(
            slice_sites, sig, a2s, scores, rem, avail, n_main, n_slice, n_clb);
    }
}

// Round 3
// 165.611 us; speedup vs baseline: 1.4124x; 1.4124x over previous
//
#include <hip/hip_runtime.h>

// Strategy: membership over the 2^23 site-id domain as a 1 MiB bitmap.
//  - mark_kernel: each block OWNS a disjoint 128-word slice of the bitmap
//    (4096 site ids). It binary-searches sorted addr2site_map for its site
//    range (block-uniform -> scalar loads), accumulates bits in an LDS
//    bitmap via LDS atomics (per-thread pre-merge over 8 consecutive sorted
//    entries cuts atomic count ~6x), then writes its words with plain
//    coalesced stores. No global atomics, no zeroing pass, full coverage.
//  - probe_kernel: vectorized scan of sorted slice_sites -> sequential,
//    cache-resident bitmap probes -> float4 outputs.

static constexpr int NUM_SITES_TOTAL = 2048 * 4096;            // 8,388,608
static constexpr int BITMAP_WORDS    = NUM_SITES_TOTAL / 32;   // 262,144 (1 MiB)
static constexpr int WORDS_PER_BLOCK = 128;                    // 512 B LDS bitmap
static constexpr int SITES_PER_BLOCK = WORDS_PER_BLOCK * 32;   // 4096 site ids
static constexpr int MARK_BLOCKS     = BITMAP_WORDS / WORDS_PER_BLOCK; // 2048
static constexpr int BLOCK           = 256;
static constexpr int CHUNK           = 8;   // consecutive entries per thread-iter

__global__ __launch_bounds__(BLOCK) void mark_kernel(
    const int* __restrict__ sig, const int* __restrict__ a2s,
    unsigned int* __restrict__ bm, int n_clb)
{
    __shared__ unsigned int lbm[WORDS_PER_BLOCK];

    const int siteBase = blockIdx.x * SITES_PER_BLOCK;
    const int siteEnd  = siteBase + SITES_PER_BLOCK;

    for (int w = threadIdx.x; w < WORDS_PER_BLOCK; w += BLOCK) lbm[w] = 0u;

    // Block-uniform binary searches (compiler scalarizes: all operands uniform).
    int lo = 0, hi = n_clb;
    while (lo < hi) { int m = (lo + hi) >> 1; if (a2s[m] < siteBase) lo = m + 1; else hi = m; }
    const int e0 = lo;
    hi = n_clb;
    while (lo < hi) { int m = (lo + hi) >> 1; if (a2s[m] < siteEnd) lo = m + 1; else hi = m; }
    const int e1 = lo;

    __syncthreads();

    // Each thread takes CHUNK consecutive (sorted) entries -> most bits land
    // in one word -> merge in registers before the LDS atomic.
    for (int s = e0 + threadIdx.x * CHUNK; s < e1; s += BLOCK * CHUNK) {
        const int end = min(s + CHUNK, e1);
        unsigned int curw = 0xFFFFFFFFu, curm = 0u;
        for (int i = s; i < end; ++i) {
            if (sig[i] > 0) {
                const unsigned int u = (unsigned int)(a2s[i] - siteBase);
                const unsigned int w = u >> 5;
                const unsigned int m = 1u << (u & 31u);
                if (w == curw) {
                    curm |= m;
                } else {
                    if (curm) atomicOr(&lbm[curw], curm);
                    curw = w; curm = m;
                }
            }
        }
        if (curm) atomicOr(&lbm[curw], curm);
    }

    __syncthreads();

    // Plain coalesced writeback of this block's disjoint word range.
    uint4* dst = (uint4*)(bm + blockIdx.x * WORDS_PER_BLOCK);
    const uint4* src = (const uint4*)lbm;
    for (int q = threadIdx.x; q < WORDS_PER_BLOCK / 4; q += BLOCK) dst[q] = src[q];
}

__global__ __launch_bounds__(BLOCK) void probe_kernel(
    const int4* __restrict__ ss, const float4* __restrict__ sc,
    const unsigned int* __restrict__ bm,
    float4* __restrict__ rem, float4* __restrict__ avail, int n4)
{
    int i = blockIdx.x * blockDim.x + threadIdx.x;
    if (i >= n4) return;
    int4 s = ss[i];
    float4 f = sc[i];
    int   sv[4] = {s.x, s.y, s.z, s.w};
    float fv[4] = {f.x, f.y, f.z, f.w};
    float rv[4], av[4];
#pragma unroll
    for (int j = 0; j < 4; ++j) {
        const unsigned int u = (unsigned int)sv[j];
        const unsigned int bit = (bm[u >> 5] >> (u & 31u)) & 1u;
        rv[j] = bit ? 0.0f : 1.0f;
        av[j] = bit ? 0.0f : fv[j];
    }
    rem[i]   = make_float4(rv[0], rv[1], rv[2], rv[3]);
    avail[i] = make_float4(av[0], av[1], av[2], av[3]);
}

__global__ void probe_tail_kernel(
    const int* __restrict__ ss, const float* __restrict__ sc,
    const unsigned int* __restrict__ bm,
    float* __restrict__ rem, float* __restrict__ avail, int start, int n)
{
    int i = start + blockIdx.x * blockDim.x + threadIdx.x;
    if (i >= n) return;
    const unsigned int u = (unsigned int)ss[i];
    const unsigned int bit = (bm[u >> 5] >> (u & 31u)) & 1u;
    rem[i]   = bit ? 0.0f : 1.0f;
    avail[i] = bit ? 0.0f : sc[i];
}

extern "C" void kernel_launch(void* const* d_in, const int* in_sizes, int n_in,
                              void* d_out, int out_size, void* d_ws, size_t ws_size,
                              hipStream_t stream) {
    const int*   slice_sites = (const int*)d_in[0];
    const int*   sig         = (const int*)d_in[1];
    const int*   a2s         = (const int*)d_in[2];
    const float* scores      = (const float*)d_in[3];
    const int n_slice = in_sizes[0];
    const int n_clb   = in_sizes[1];

    unsigned int* bm = (unsigned int*)d_ws;  // 1 MiB bitmap, fully written by mark_kernel

    mark_kernel<<<MARK_BLOCKS, BLOCK, 0, stream>>>(sig, a2s, bm, n_clb);

    float* rem   = (float*)d_out;
    float* avail = rem + n_slice;
    const int n4 = n_slice / 4;
    if (n4 > 0)
        probe_kernel<<<(n4 + BLOCK - 1) / BLOCK, BLOCK, 0, stream>>>(
            (const int4*)slice_sites, (const float4*)scores, bm,
            (float4*)rem, (float4*)avail, n4);
    if (n4 * 4 < n_slice)
        probe_tail_kernel<<<1, 64, 0, stream>>>(slice_sites, scores, bm,
                                                rem, avail, n4 * 4, n_slice);
}

// Round 5
// 151.547 us; speedup vs baseline: 1.5434x; 1.0928x over previous
//
#include <hip/hip_runtime.h>

// Bitmap membership over the 2^23 site-id domain.
//  mark_kernel: block g owns bitmap words [g*128,(g+1)*128) = 4096 site ids.
//    Binary-search sorted addr2site_map for the site range (uniform -> scalar),
//    scan entries with 4x vec4 vector loads per thread (16 entries), merge
//    bits in registers, LDS atomicOr, then plain coalesced writeback.
//  probe_kernel: 8 elems/thread, NT streaming loads/stores, cached bitmap.

typedef int   v4i __attribute__((ext_vector_type(4)));   // clang-native vectors:
typedef float v4f __attribute__((ext_vector_type(4)));   // accepted by nontemporal builtins

static constexpr int NUM_SITES_TOTAL = 2048 * 4096;            // 8,388,608
static constexpr int BITMAP_WORDS    = NUM_SITES_TOTAL / 32;   // 262,144
static constexpr int WORDS_PER_BLOCK = 128;                    // 512 B LDS
static constexpr int SITES_PER_BLOCK = WORDS_PER_BLOCK * 32;   // 4096
static constexpr int MARK_BLOCKS     = BITMAP_WORDS / WORDS_PER_BLOCK; // 2048
static constexpr int BLOCK           = 256;
static constexpr int CHUNK           = 16;  // entries/thread/iter (4 x v4i)

__global__ __launch_bounds__(BLOCK) void mark_kernel(
    const int* __restrict__ sig, const int* __restrict__ a2s,
    unsigned int* __restrict__ bm, int n_clb)
{
    __shared__ unsigned int lbm[WORDS_PER_BLOCK];

    const int siteBase = blockIdx.x * SITES_PER_BLOCK;
    const int siteEnd  = siteBase + SITES_PER_BLOCK;

    for (int w = threadIdx.x; w < WORDS_PER_BLOCK; w += BLOCK) lbm[w] = 0u;

    // Uniform binary searches for the entry range [e0, e1).
    int lo = 0, hi = n_clb;
    while (lo < hi) { int m = (lo + hi) >> 1; if (a2s[m] < siteBase) lo = m + 1; else hi = m; }
    const int e0 = lo;
    hi = n_clb;
    while (lo < hi) { int m = (lo + hi) >> 1; if (a2s[m] < siteEnd) lo = m + 1; else hi = m; }
    const int e1 = lo;

    __syncthreads();

    // Align the scan start so vec4 loads are 16B-aligned. Entries outside
    // [e0,e1) fail the site-range check (they belong to neighbor blocks).
    const int start = e0 & ~(CHUNK - 1);

    for (int s = start + threadIdx.x * CHUNK; s < e1; s += BLOCK * CHUNK) {
        int av[CHUNK], gv[CHUNK];
        if (s + CHUNK <= n_clb) {
            const v4i* ap = (const v4i*)(a2s + s);
            const v4i* gp = (const v4i*)(sig + s);
#pragma unroll
            for (int q = 0; q < CHUNK / 4; ++q) {
                v4i a = ap[q];
                av[4*q+0] = a.x; av[4*q+1] = a.y; av[4*q+2] = a.z; av[4*q+3] = a.w;
                v4i g = gp[q];
                gv[4*q+0] = g.x; gv[4*q+1] = g.y; gv[4*q+2] = g.z; gv[4*q+3] = g.w;
            }
        } else {
#pragma unroll
            for (int j = 0; j < CHUNK; ++j) {
                const int i = s + j;
                const bool ok = i < n_clb;
                av[j] = ok ? a2s[i] : -1;   // -1 fails the range check
                gv[j] = ok ? sig[i] : 0;
            }
        }

        unsigned int curw = 0xFFFFFFFFu, curm = 0u;
#pragma unroll
        for (int j = 0; j < CHUNK; ++j) {
            const int site = av[j];
            if (gv[j] > 0 && site >= siteBase && site < siteEnd) {
                const unsigned int u = (unsigned int)(site - siteBase);
                const unsigned int w = u >> 5;
                const unsigned int m = 1u << (u & 31u);
                if (w == curw) {
                    curm |= m;
                } else {
                    if (curm) atomicOr(&lbm[curw], curm);
                    curw = w; curm = m;
                }
            }
        }
        if (curm) atomicOr(&lbm[curw], curm);
    }

    __syncthreads();

    uint4* dst = (uint4*)(bm + blockIdx.x * WORDS_PER_BLOCK);
    const uint4* src = (const uint4*)lbm;
    for (int q = threadIdx.x; q < WORDS_PER_BLOCK / 4; q += BLOCK) dst[q] = src[q];
}

__global__ __launch_bounds__(BLOCK) void probe_kernel(
    const int* __restrict__ ss, const float* __restrict__ sc,
    const unsigned int* __restrict__ bm,
    float* __restrict__ rem, float* __restrict__ avail, int n8)
{
    const int t = blockIdx.x * BLOCK + threadIdx.x;
    if (t >= n8) return;
    const int base = t * 8;

    const v4i* sp = (const v4i*)(ss + base);
    const v4f* cp = (const v4f*)(sc + base);
    v4i s01 = __builtin_nontemporal_load(sp);
    v4i s23 = __builtin_nontemporal_load(sp + 1);
    v4f f01 = __builtin_nontemporal_load(cp);
    v4f f23 = __builtin_nontemporal_load(cp + 1);

    int   sv[8] = {s01.x, s01.y, s01.z, s01.w, s23.x, s23.y, s23.z, s23.w};
    float fv[8] = {f01.x, f01.y, f01.z, f01.w, f23.x, f23.y, f23.z, f23.w};
    float rv[8], av[8];
#pragma unroll
    for (int j = 0; j < 8; ++j) {
        const unsigned int u = (unsigned int)sv[j];
        const unsigned int bit = (bm[u >> 5] >> (u & 31u)) & 1u;
        rv[j] = bit ? 0.0f : 1.0f;
        av[j] = bit ? 0.0f : fv[j];
    }

    v4f* rp = (v4f*)(rem + base);
    v4f* ap = (v4f*)(avail + base);
    v4f r0 = {rv[0], rv[1], rv[2], rv[3]};
    v4f r1 = {rv[4], rv[5], rv[6], rv[7]};
    v4f a0 = {av[0], av[1], av[2], av[3]};
    v4f a1 = {av[4], av[5], av[6], av[7]};
    __builtin_nontemporal_store(r0, rp);
    __builtin_nontemporal_store(r1, rp + 1);
    __builtin_nontemporal_store(a0, ap);
    __builtin_nontemporal_store(a1, ap + 1);
}

__global__ void probe_tail_kernel(
    const int* __restrict__ ss, const float* __restrict__ sc,
    const unsigned int* __restrict__ bm,
    float* __restrict__ rem, float* __restrict__ avail, int start, int n)
{
    const int i = start + blockIdx.x * blockDim.x + threadIdx.x;
    if (i >= n) return;
    const unsigned int u = (unsigned int)ss[i];
    const unsigned int bit = (bm[u >> 5] >> (u & 31u)) & 1u;
    rem[i]   = bit ? 0.0f : 1.0f;
    avail[i] = bit ? 0.0f : sc[i];
}

extern "C" void kernel_launch(void* const* d_in, const int* in_sizes, int n_in,
                              void* d_out, int out_size, void* d_ws, size_t ws_size,
                              hipStream_t stream) {
    const int*   slice_sites = (const int*)d_in[0];
    const int*   sig         = (const int*)d_in[1];
    const int*   a2s         = (const int*)d_in[2];
    const float* scores      = (const float*)d_in[3];
    const int n_slice = in_sizes[0];
    const int n_clb   = in_sizes[1];

    unsigned int* bm = (unsigned int*)d_ws;  // 1 MiB bitmap, fully covered by mark

    mark_kernel<<<MARK_BLOCKS, BLOCK, 0, stream>>>(sig, a2s, bm, n_clb);

    float* rem   = (float*)d_out;
    float* avail = rem + n_slice;
    const int n8 = n_slice / 8;
    if (n8 > 0)
        probe_kernel<<<(n8 + BLOCK - 1) / BLOCK, BLOCK, 0, stream>>>(
            slice_sites, scores, bm, rem, avail, n8);
    if (n8 * 8 < n_slice)
        probe_tail_kernel<<<1, 64, 0, stream>>>(slice_sites, scores, bm,
                                                rem, avail, n8 * 8, n_slice);
}